// Round 11
// baseline (240.025 us; speedup 1.0000x reference)
//
#include <hip/hip_runtime.h>
#include <math.h>

#define N_NODES 50000
#define N_EDGES 800000
#define IN_CH 128
#define NBUCK 196        // ceil(50000/256): bucket = 256 consecutive dst nodes
#define BCAP 5120        // per-bucket capacity
#define EPB 4082         // edges per binA block: 196*4082 >= 800000

typedef unsigned short ushort_t;
typedef unsigned int uint_t;
typedef __attribute__((ext_vector_type(8))) short bf16x8;
typedef __attribute__((ext_vector_type(4))) float f32x4;

static __device__ __forceinline__ ushort_t f32_to_bf16(float f) {
    uint_t u = __float_as_uint(f);
    uint_t r = (u + 0x7fffu + ((u >> 16) & 1u)) >> 16;  // RNE
    return (ushort_t)r;
}

static __device__ __forceinline__ void acc8(float* a, uint4 v) {
    a[0] += __uint_as_float(v.x << 16); a[1] += __uint_as_float(v.x & 0xffff0000u);
    a[2] += __uint_as_float(v.y << 16); a[3] += __uint_as_float(v.y & 0xffff0000u);
    a[4] += __uint_as_float(v.z << 16); a[5] += __uint_as_float(v.z & 0xffff0000u);
    a[6] += __uint_as_float(v.w << 16); a[7] += __uint_as_float(v.w & 0xffff0000u);
}

// ---------------------------------------------------------------------------
// Phase A: bin edges into 196 dst-range buckets. pair = (dst&255)<<16 | src
// ---------------------------------------------------------------------------
__global__ __launch_bounds__(256) void binA(
    const int* __restrict__ src, const int* __restrict__ dst,
    uint_t* __restrict__ gbcnt, uint_t* __restrict__ gbuck) {
    __shared__ uint_t hist[NBUCK];
    __shared__ uint_t excl_s[NBUCK];
    __shared__ uint_t gbase[NBUCK];
    __shared__ uint_t cur[NBUCK];
    __shared__ uint_t pfx[256];
    __shared__ uint_t stage[4096];
    __shared__ uint_t gpos[4096];
    const int t = threadIdx.x;
    const int e0 = blockIdx.x * EPB;
    const int e1 = min(e0 + EPB, N_EDGES);

    for (int i = t; i < NBUCK; i += 256) hist[i] = 0;
    __syncthreads();
    for (int e = e0 + t; e < e1; e += 256) atomicAdd(&hist[dst[e] >> 8], 1u);
    __syncthreads();
    uint_t own = (t < NBUCK) ? hist[t] : 0;
    pfx[t] = own;
    __syncthreads();
    for (int d = 1; d < 256; d <<= 1) {
        uint_t v = (t >= d) ? pfx[t - d] : 0;
        __syncthreads();
        pfx[t] += v;
        __syncthreads();
    }
    if (t < NBUCK) {
        uint_t excl = pfx[t] - own;
        excl_s[t] = excl;
        cur[t] = excl;
        gbase[t] = atomicAdd(&gbcnt[t], own);
    }
    __syncthreads();
    for (int e = e0 + t; e < e1; e += 256) {
        int d_ = dst[e];
        int b = d_ >> 8;
        uint_t p = atomicAdd(&cur[b], 1u);
        stage[p] = ((uint_t)(d_ & 255) << 16) | (uint_t)src[e];
        gpos[p] = (uint_t)b * BCAP + gbase[b] + (p - excl_s[b]);
    }
    __syncthreads();
    const int n = e1 - e0;
    for (int i = t; i < n; i += 256) gbuck[gpos[i]] = stage[i];
}

// ---------------------------------------------------------------------------
// Phase B (merged): per bucket -> offs (node CSR offsets) + ebuf (src lists).
// ---------------------------------------------------------------------------
__global__ __launch_bounds__(256) void binB(
    const uint_t* __restrict__ gbcnt, const uint_t* __restrict__ gbuck,
    int* __restrict__ offs, int* __restrict__ ebuf) {
    __shared__ uint_t pairs[BCAP];   // 20 KB
    __shared__ int stage[BCAP];      // 20 KB
    __shared__ uint_t bscan[256];
    __shared__ uint_t h[256];
    __shared__ uint_t psc[256];
    __shared__ int cur[256];
    const int b = blockIdx.x;
    const int t = threadIdx.x;

    uint_t g = (t < NBUCK) ? gbcnt[t] : 0;
    bscan[t] = g;
    __syncthreads();
    for (int d = 1; d < 256; d <<= 1) {
        uint_t v = (t >= d) ? bscan[t - d] : 0;
        __syncthreads();
        bscan[t] += v;
        __syncthreads();
    }
    const int base = (b > 0) ? (int)bscan[b - 1] : 0;
    const uint_t n = gbcnt[b];

    for (uint_t i = t; i < n; i += 256) pairs[i] = gbuck[(size_t)b * BCAP + i];
    h[t] = 0;
    __syncthreads();
    for (uint_t i = t; i < n; i += 256) atomicAdd(&h[(pairs[i] >> 16) & 255u], 1u);
    __syncthreads();
    uint_t own = h[t];
    psc[t] = own;
    __syncthreads();
    for (int d = 1; d < 256; d <<= 1) {
        uint_t v = (t >= d) ? psc[t - d] : 0;
        __syncthreads();
        psc[t] += v;
        __syncthreads();
    }
    const int excl = (int)(psc[t] - own);
    const int node = b * 256 + t;
    if (node <= N_NODES) offs[node] = base + excl;
    cur[t] = excl;
    __syncthreads();
    for (uint_t i = t; i < n; i += 256) {
        uint_t p = pairs[i];
        int l = (p >> 16) & 255;
        int pos = atomicAdd(&cur[l], 1);
        stage[pos] = (int)(p & 0xFFFFu);
    }
    __syncthreads();
    for (uint_t i = t; i < n; i += 256) ebuf[base + (int)i] = stage[i];
}

// ---------------------------------------------------------------------------
// convert x f32 -> bf16 (one pass); also zeroes gbcnt for binA
// ---------------------------------------------------------------------------
__global__ __launch_bounds__(256) void cvt_x(const float* __restrict__ x,
                                             ushort_t* __restrict__ xb,
                                             uint_t* __restrict__ gbcnt, int n8) {
    int i = blockIdx.x * 256 + threadIdx.x;
    if (blockIdx.x == 0 && threadIdx.x < NBUCK) gbcnt[threadIdx.x] = 0;
    if (i >= n8) return;
    const float* p = x + (size_t)i * 8;
    float4 lo = *(const float4*)p;
    float4 hi = *(const float4*)(p + 4);
    bf16x8 r;
    r[0] = (short)f32_to_bf16(lo.x); r[1] = (short)f32_to_bf16(lo.y);
    r[2] = (short)f32_to_bf16(lo.z); r[3] = (short)f32_to_bf16(lo.w);
    r[4] = (short)f32_to_bf16(hi.x); r[5] = (short)f32_to_bf16(hi.y);
    r[6] = (short)f32_to_bf16(hi.z); r[7] = (short)f32_to_bf16(hi.w);
    *(bf16x8*)&xb[(size_t)i * 8] = r;
}

// ---------------------------------------------------------------------------
// weight prep (all 3 layers): Bt[c][k] stacked [Wl;Wr], K-contiguous, bf16
// ---------------------------------------------------------------------------
__global__ __launch_bounds__(256) void prep_all(
    const float* __restrict__ Wl0, const float* __restrict__ Wr0,
    const float* __restrict__ Wl1, const float* __restrict__ Wr1,
    const float* __restrict__ Wl2, const float* __restrict__ Wr2,
    ushort_t* __restrict__ Bt0, ushort_t* __restrict__ Bt1,
    ushort_t* __restrict__ Bt2) {
    int i = blockIdx.x * 256 + threadIdx.x;
    const float* Wl;
    const float* Wr;
    ushort_t* Bt;
    int C;
    if (i < 32768) {
        Wl = Wl0; Wr = Wr0; Bt = Bt0; C = 128;
    } else if (i < 65536) {
        i -= 32768; Wl = Wl1; Wr = Wr1; Bt = Bt1; C = 128;
    } else if (i < 81920) {
        i -= 65536; Wl = Wl2; Wr = Wr2; Bt = Bt2; C = 64;
    } else {
        return;
    }
    int c = i / 256, k = i % 256;
    float v = (k < 128) ? Wl[(size_t)k * C + c] : Wr[(size_t)(k - 128) * C + c];
    Bt[i] = f32_to_bf16(v);
}

// ---------------------------------------------------------------------------
// FUSED layer: block = 64 dst nodes. Phase 1: 4 waves mean-aggregate 16 nodes
// each into LDS Ms[64][136] (bf16, +8 pad = conflict-free b128 reads).
// Phase 2: out = [Ms | X] @ Bt^T + bias (K=256), optional ELU, bf16/f32 out.
// ---------------------------------------------------------------------------
template <int C, bool ELU, bool OUT_F32>
__global__ __launch_bounds__(256) void sage_layer(
    const int* __restrict__ offs, const int* __restrict__ ebuf,
    const ushort_t* __restrict__ X, const ushort_t* __restrict__ Bt,
    const float* __restrict__ bias, void* __restrict__ out_v, int nNodes) {
    __shared__ ushort_t Ms[64][136];     // 17.4 KB
    constexpr int NI = C / 32;           // 16-col subtiles per wave
    const int tid = threadIdx.x;
    const int wave = tid >> 6, lane = tid & 63;
    const int n0 = blockIdx.x * 64;

    // ---- phase 1: gather means into LDS ----
    {
        const int q = lane >> 4;           // quarter owns neighbor j+q (stride 4)
        const int cl = (lane & 15) * 8;    // 8 channels per lane
        for (int i = 0; i < 16; ++i) {
            const int row = wave * 16 + i;
            const int wid = n0 + row;
            if (wid >= nNodes) break;
            const int o0 = offs[wid], o1 = offs[wid + 1];
            const float inv = 1.0f / fmaxf((float)(o1 - o0), 1.0f);
            float a0[8] = {0.f, 0.f, 0.f, 0.f, 0.f, 0.f, 0.f, 0.f};
            float a1[8] = {0.f, 0.f, 0.f, 0.f, 0.f, 0.f, 0.f, 0.f};
            int j = o0;
            for (; j + 8 <= o1; j += 8) {
                int s0 = ebuf[j + q];
                int s1 = ebuf[j + 4 + q];
                uint4 v0 = *(const uint4*)&X[(size_t)s0 * 128 + cl];
                uint4 v1 = *(const uint4*)&X[(size_t)s1 * 128 + cl];
                acc8(a0, v0);
                acc8(a1, v1);
            }
            if (j + 4 <= o1) {
                int s0 = ebuf[j + q];
                uint4 v0 = *(const uint4*)&X[(size_t)s0 * 128 + cl];
                acc8(a0, v0);
                j += 4;
            }
            if (j + q < o1) {
                int s1 = ebuf[j + q];
                uint4 v1 = *(const uint4*)&X[(size_t)s1 * 128 + cl];
                acc8(a1, v1);
            }
#pragma unroll
            for (int k = 0; k < 8; ++k) a0[k] += a1[k];
#pragma unroll
            for (int k = 0; k < 8; ++k) {
                a0[k] += __shfl_xor(a0[k], 16);
                a0[k] += __shfl_xor(a0[k], 32);
            }
            if (lane < 16) {
                uint4 o;
                o.x = (uint_t)f32_to_bf16(a0[0] * inv) | ((uint_t)f32_to_bf16(a0[1] * inv) << 16);
                o.y = (uint_t)f32_to_bf16(a0[2] * inv) | ((uint_t)f32_to_bf16(a0[3] * inv) << 16);
                o.z = (uint_t)f32_to_bf16(a0[4] * inv) | ((uint_t)f32_to_bf16(a0[5] * inv) << 16);
                o.w = (uint_t)f32_to_bf16(a0[6] * inv) | ((uint_t)f32_to_bf16(a0[7] * inv) << 16);
                *(uint4*)&Ms[row][cl] = o;
            }
        }
    }
    __syncthreads();

    // ---- phase 2: GEMM [Ms | X] @ Bt^T ----
    const int lrow = lane & 15, lgrp = lane >> 4;
    const int rloc = (wave >> 1) * 32;       // local row base (0 or 32)
    const int colbase = (wave & 1) * (C / 2);

    f32x4 acc[2][NI] = {};

#pragma unroll
    for (int half = 0; half < 2; ++half) {
#pragma unroll
        for (int ks = 0; ks < 4; ++ks) {
            const int k0 = ks * 32 + lgrp * 8;
            bf16x8 a[2], bf[NI];
#pragma unroll
            for (int mi = 0; mi < 2; ++mi) {
                if (half == 0) {
                    a[mi] = *(const bf16x8*)&Ms[rloc + mi * 16 + lrow][k0];
                } else {
                    int r = n0 + rloc + mi * 16 + lrow;
                    r = min(r, nNodes - 1);
                    a[mi] = *(const bf16x8*)&X[(size_t)r * 128 + k0];
                }
            }
#pragma unroll
            for (int ni = 0; ni < NI; ++ni) {
                int c = colbase + ni * 16 + lrow;
                bf[ni] = *(const bf16x8*)&Bt[(size_t)c * 256 + half * 128 + k0];
            }
#pragma unroll
            for (int mi = 0; mi < 2; ++mi)
#pragma unroll
                for (int ni = 0; ni < NI; ++ni)
                    acc[mi][ni] = __builtin_amdgcn_mfma_f32_16x16x32_bf16(
                        a[mi], bf[ni], acc[mi][ni], 0, 0, 0);
        }
    }

    // epilogue: C/D layout col=lane&15, row=(lane>>4)*4+reg (m89-verified)
#pragma unroll
    for (int ni = 0; ni < NI; ++ni) {
        const int c = colbase + ni * 16 + lrow;
        const float bv = bias[c];
#pragma unroll
        for (int mi = 0; mi < 2; ++mi) {
#pragma unroll
            for (int j = 0; j < 4; ++j) {
                int r = n0 + rloc + mi * 16 + lgrp * 4 + j;
                if (r >= nNodes) continue;
                float v = acc[mi][ni][j] + bv;
                if (ELU) v = v > 0.f ? v : expm1f(v);
                if (OUT_F32) ((float*)out_v)[(size_t)r * C + c] = v;
                else ((ushort_t*)out_v)[(size_t)r * C + c] = f32_to_bf16(v);
            }
        }
    }
}

// ---------------------------------------------------------------------------
extern "C" void kernel_launch(void* const* d_in, const int* in_sizes, int n_in,
                              void* d_out, int out_size, void* d_ws, size_t ws_size,
                              hipStream_t stream) {
    const float* x = (const float*)d_in[0];
    const int* ei = (const int*)d_in[1];
    const int* src = ei;
    const int* dst = ei + N_EDGES;
    const float* Wl0 = (const float*)d_in[2];
    const float* Wr0 = (const float*)d_in[3];
    const float* b0 = (const float*)d_in[4];
    const float* Wl1 = (const float*)d_in[5];
    const float* Wr1 = (const float*)d_in[6];
    const float* b1 = (const float*)d_in[7];
    const float* Wl2 = (const float*)d_in[8];
    const float* Wr2 = (const float*)d_in[9];
    const float* b2 = (const float*)d_in[10];
    float* out = (float*)d_out;

    // workspace layout (int units)
    int* wsi = (int*)d_ws;
    int* offs = wsi;                               // 51200
    uint_t* gbcnt = (uint_t*)(offs + 51200);       // 256
    int* ebuf = (int*)(gbcnt + 256);               // 800000
    uint_t* gbuck = (uint_t*)(ebuf + 800000);      // NBUCK*BCAP = 1,003,520
    ushort_t* Bt0 = (ushort_t*)(gbuck + NBUCK * BCAP);  // 128*256
    ushort_t* Bt1 = Bt0 + 128 * 256;                    // 128*256
    ushort_t* Bt2 = Bt1 + 128 * 256;                    // 64*256
    const long long NB = (long long)N_NODES * 128;
    ushort_t* xb = Bt2 + 64 * 256;                 // [N*128] bf16
    ushort_t* hA = xb + NB;                        // [N*128] bf16
    ushort_t* hB = hA + NB;                        // [N*128] bf16

    // ---- prep: x->bf16 (+ gbcnt zero), stacked bf16 weights ----
    cvt_x<<<(N_NODES * 16 + 255) / 256, 256, 0, stream>>>(x, xb, gbcnt, N_NODES * 16);
    prep_all<<<(81920 + 255) / 256, 256, 0, stream>>>(
        Wl0, Wr0, Wl1, Wr1, Wl2, Wr2, Bt0, Bt1, Bt2);

    // ---- build CSR: 2 kernels ----
    binA<<<NBUCK, 256, 0, stream>>>(src, dst, gbcnt, gbuck);
    binB<<<NBUCK, 256, 0, stream>>>(gbcnt, gbuck, offs, ebuf);

    const int GR = (N_NODES + 63) / 64;            // 782 node panels

    // ---- 3 fused layers ----
    sage_layer<128, true, false><<<GR, 256, 0, stream>>>(
        offs, ebuf, xb, Bt0, b0, hA, N_NODES);
    sage_layer<128, true, false><<<GR, 256, 0, stream>>>(
        offs, ebuf, hA, Bt1, b1, hB, N_NODES);
    sage_layer<64, false, true><<<GR, 256, 0, stream>>>(
        offs, ebuf, hB, Bt2, b2, out, N_NODES);
}

// Round 13
// 228.987 us; speedup vs baseline: 1.0482x; 1.0482x over previous
//
#include <hip/hip_runtime.h>
#include <math.h>

#define N_NODES 50000
#define N_EDGES 800000
#define IN_CH 128
#define NBUCK 196        // ceil(50000/256): bucket = 256 consecutive dst nodes
#define BCAP 5120        // per-bucket capacity
#define EPB 4082         // edges per binA block: 196*4082 >= 800000

typedef unsigned short ushort_t;
typedef unsigned int uint_t;
typedef __attribute__((ext_vector_type(8))) short bf16x8;
typedef __attribute__((ext_vector_type(4))) float f32x4;

static __device__ __forceinline__ ushort_t f32_to_bf16(float f) {
    uint_t u = __float_as_uint(f);
    uint_t r = (u + 0x7fffu + ((u >> 16) & 1u)) >> 16;  // RNE
    return (ushort_t)r;
}

static __device__ __forceinline__ void acc8(float* a, uint4 v) {
    a[0] += __uint_as_float(v.x << 16); a[1] += __uint_as_float(v.x & 0xffff0000u);
    a[2] += __uint_as_float(v.y << 16); a[3] += __uint_as_float(v.y & 0xffff0000u);
    a[4] += __uint_as_float(v.z << 16); a[5] += __uint_as_float(v.z & 0xffff0000u);
    a[6] += __uint_as_float(v.w << 16); a[7] += __uint_as_float(v.w & 0xffff0000u);
}

// ---------------------------------------------------------------------------
// Phase A: bin edges into 196 dst-range buckets. pair = (dst&255)<<16 | src
// ---------------------------------------------------------------------------
__global__ __launch_bounds__(256) void binA(
    const int* __restrict__ src, const int* __restrict__ dst,
    uint_t* __restrict__ gbcnt, uint_t* __restrict__ gbuck) {
    __shared__ uint_t hist[NBUCK];
    __shared__ uint_t excl_s[NBUCK];
    __shared__ uint_t gbase[NBUCK];
    __shared__ uint_t cur[NBUCK];
    __shared__ uint_t pfx[256];
    __shared__ uint_t stage[4096];
    __shared__ uint_t gpos[4096];
    const int t = threadIdx.x;
    const int e0 = blockIdx.x * EPB;
    const int e1 = min(e0 + EPB, N_EDGES);

    for (int i = t; i < NBUCK; i += 256) hist[i] = 0;
    __syncthreads();
    for (int e = e0 + t; e < e1; e += 256) atomicAdd(&hist[dst[e] >> 8], 1u);
    __syncthreads();
    uint_t own = (t < NBUCK) ? hist[t] : 0;
    pfx[t] = own;
    __syncthreads();
    for (int d = 1; d < 256; d <<= 1) {
        uint_t v = (t >= d) ? pfx[t - d] : 0;
        __syncthreads();
        pfx[t] += v;
        __syncthreads();
    }
    if (t < NBUCK) {
        uint_t excl = pfx[t] - own;
        excl_s[t] = excl;
        cur[t] = excl;
        gbase[t] = atomicAdd(&gbcnt[t], own);
    }
    __syncthreads();
    for (int e = e0 + t; e < e1; e += 256) {
        int d_ = dst[e];
        int b = d_ >> 8;
        uint_t p = atomicAdd(&cur[b], 1u);
        stage[p] = ((uint_t)(d_ & 255) << 16) | (uint_t)src[e];
        gpos[p] = (uint_t)b * BCAP + gbase[b] + (p - excl_s[b]);
    }
    __syncthreads();
    const int n = e1 - e0;
    for (int i = t; i < n; i += 256) gbuck[gpos[i]] = stage[i];
}

// ---------------------------------------------------------------------------
// Phase B (merged): per bucket -> offs (node CSR offsets) + ebuf (src lists).
// ---------------------------------------------------------------------------
__global__ __launch_bounds__(256) void binB(
    const uint_t* __restrict__ gbcnt, const uint_t* __restrict__ gbuck,
    int* __restrict__ offs, int* __restrict__ ebuf) {
    __shared__ uint_t pairs[BCAP];   // 20 KB
    __shared__ int stage[BCAP];      // 20 KB
    __shared__ uint_t bscan[256];
    __shared__ uint_t h[256];
    __shared__ uint_t psc[256];
    __shared__ int cur[256];
    const int b = blockIdx.x;
    const int t = threadIdx.x;

    uint_t g = (t < NBUCK) ? gbcnt[t] : 0;
    bscan[t] = g;
    __syncthreads();
    for (int d = 1; d < 256; d <<= 1) {
        uint_t v = (t >= d) ? bscan[t - d] : 0;
        __syncthreads();
        bscan[t] += v;
        __syncthreads();
    }
    const int base = (b > 0) ? (int)bscan[b - 1] : 0;
    const uint_t n = gbcnt[b];

    for (uint_t i = t; i < n; i += 256) pairs[i] = gbuck[(size_t)b * BCAP + i];
    h[t] = 0;
    __syncthreads();
    for (uint_t i = t; i < n; i += 256) atomicAdd(&h[(pairs[i] >> 16) & 255u], 1u);
    __syncthreads();
    uint_t own = h[t];
    psc[t] = own;
    __syncthreads();
    for (int d = 1; d < 256; d <<= 1) {
        uint_t v = (t >= d) ? psc[t - d] : 0;
        __syncthreads();
        psc[t] += v;
        __syncthreads();
    }
    const int excl = (int)(psc[t] - own);
    const int node = b * 256 + t;
    if (node <= N_NODES) offs[node] = base + excl;
    cur[t] = excl;
    __syncthreads();
    for (uint_t i = t; i < n; i += 256) {
        uint_t p = pairs[i];
        int l = (p >> 16) & 255;
        int pos = atomicAdd(&cur[l], 1);
        stage[pos] = (int)(p & 0xFFFFu);
    }
    __syncthreads();
    for (uint_t i = t; i < n; i += 256) ebuf[base + (int)i] = stage[i];
}

// ---------------------------------------------------------------------------
// convert x f32 -> bf16 (one pass); also zeroes gbcnt for binA
// ---------------------------------------------------------------------------
__global__ __launch_bounds__(256) void cvt_x(const float* __restrict__ x,
                                             ushort_t* __restrict__ xb,
                                             uint_t* __restrict__ gbcnt, int n8) {
    int i = blockIdx.x * 256 + threadIdx.x;
    if (blockIdx.x == 0 && threadIdx.x < NBUCK) gbcnt[threadIdx.x] = 0;
    if (i >= n8) return;
    const float* p = x + (size_t)i * 8;
    float4 lo = *(const float4*)p;
    float4 hi = *(const float4*)(p + 4);
    bf16x8 r;
    r[0] = (short)f32_to_bf16(lo.x); r[1] = (short)f32_to_bf16(lo.y);
    r[2] = (short)f32_to_bf16(lo.z); r[3] = (short)f32_to_bf16(lo.w);
    r[4] = (short)f32_to_bf16(hi.x); r[5] = (short)f32_to_bf16(hi.y);
    r[6] = (short)f32_to_bf16(hi.z); r[7] = (short)f32_to_bf16(hi.w);
    *(bf16x8*)&xb[(size_t)i * 8] = r;
}

// ---------------------------------------------------------------------------
// weight prep (all 3 layers): Bt[c][k] stacked [Wl;Wr], K-contiguous, bf16
// ---------------------------------------------------------------------------
__global__ __launch_bounds__(256) void prep_all(
    const float* __restrict__ Wl0, const float* __restrict__ Wr0,
    const float* __restrict__ Wl1, const float* __restrict__ Wr1,
    const float* __restrict__ Wl2, const float* __restrict__ Wr2,
    ushort_t* __restrict__ Bt0, ushort_t* __restrict__ Bt1,
    ushort_t* __restrict__ Bt2) {
    int i = blockIdx.x * 256 + threadIdx.x;
    const float* Wl;
    const float* Wr;
    ushort_t* Bt;
    int C;
    if (i < 32768) {
        Wl = Wl0; Wr = Wr0; Bt = Bt0; C = 128;
    } else if (i < 65536) {
        i -= 32768; Wl = Wl1; Wr = Wr1; Bt = Bt1; C = 128;
    } else if (i < 81920) {
        i -= 65536; Wl = Wl2; Wr = Wr2; Bt = Bt2; C = 64;
    } else {
        return;
    }
    int c = i / 256, k = i % 256;
    float v = (k < 128) ? Wl[(size_t)k * C + c] : Wr[(size_t)(k - 128) * C + c];
    Bt[i] = f32_to_bf16(v);
}

// ---------------------------------------------------------------------------
// mean-aggregate gather: M[node] = mean(feat[neighbors]) (bf16 in/out).
// One wave per node (grid-stride). Quarter q owns neighbor j+4k+q; 16B/lane.
// 16 neighbors (4KB) in flight per round. (round-10 proven version)
// ---------------------------------------------------------------------------
__global__ __launch_bounds__(256) void gather_mean(
    const int* __restrict__ offs, const int* __restrict__ ebuf,
    const ushort_t* __restrict__ feat, ushort_t* __restrict__ M, int nNodes) {
    const int wl = threadIdx.x >> 6;
    const int lane = threadIdx.x & 63;
    const int q = lane >> 4;           // quarter owns neighbor j+4k+q
    const int cl = (lane & 15) * 8;    // 8 channels per lane
    const int nw = gridDim.x * 4;

    for (int wid = blockIdx.x * 4 + wl; wid < nNodes; wid += nw) {
        const int o0 = offs[wid], o1 = offs[wid + 1];
        const float inv = 1.0f / fmaxf((float)(o1 - o0), 1.0f);
        float a0[8] = {0.f, 0.f, 0.f, 0.f, 0.f, 0.f, 0.f, 0.f};
        float a1[8] = {0.f, 0.f, 0.f, 0.f, 0.f, 0.f, 0.f, 0.f};
        float a2[8] = {0.f, 0.f, 0.f, 0.f, 0.f, 0.f, 0.f, 0.f};
        float a3[8] = {0.f, 0.f, 0.f, 0.f, 0.f, 0.f, 0.f, 0.f};
        int j = o0;
        for (; j + 16 <= o1; j += 16) {
            int s0 = ebuf[j + q];
            int s1 = ebuf[j + 4 + q];
            int s2 = ebuf[j + 8 + q];
            int s3 = ebuf[j + 12 + q];
            uint4 v0 = *(const uint4*)&feat[(size_t)s0 * 128 + cl];
            uint4 v1 = *(const uint4*)&feat[(size_t)s1 * 128 + cl];
            uint4 v2 = *(const uint4*)&feat[(size_t)s2 * 128 + cl];
            uint4 v3 = *(const uint4*)&feat[(size_t)s3 * 128 + cl];
            acc8(a0, v0); acc8(a1, v1); acc8(a2, v2); acc8(a3, v3);
        }
        for (; j + 8 <= o1; j += 8) {
            int s0 = ebuf[j + q];
            int s1 = ebuf[j + 4 + q];
            uint4 v0 = *(const uint4*)&feat[(size_t)s0 * 128 + cl];
            uint4 v1 = *(const uint4*)&feat[(size_t)s1 * 128 + cl];
            acc8(a0, v0); acc8(a1, v1);
        }
        if (j + 4 <= o1) {
            int s2 = ebuf[j + q];
            uint4 v2 = *(const uint4*)&feat[(size_t)s2 * 128 + cl];
            acc8(a2, v2);
            j += 4;
        }
        if (j + q < o1) {
            int s3 = ebuf[j + q];
            uint4 v3 = *(const uint4*)&feat[(size_t)s3 * 128 + cl];
            acc8(a3, v3);
        }
#pragma unroll
        for (int k = 0; k < 8; ++k) a0[k] += a1[k] + (a2[k] + a3[k]);
#pragma unroll
        for (int k = 0; k < 8; ++k) {
            a0[k] += __shfl_xor(a0[k], 16);
            a0[k] += __shfl_xor(a0[k], 32);
        }
        if (lane < 16) {
            uint4 o;
            o.x = (uint_t)f32_to_bf16(a0[0] * inv) | ((uint_t)f32_to_bf16(a0[1] * inv) << 16);
            o.y = (uint_t)f32_to_bf16(a0[2] * inv) | ((uint_t)f32_to_bf16(a0[3] * inv) << 16);
            o.z = (uint_t)f32_to_bf16(a0[4] * inv) | ((uint_t)f32_to_bf16(a0[5] * inv) << 16);
            o.w = (uint_t)f32_to_bf16(a0[6] * inv) | ((uint_t)f32_to_bf16(a0[7] * inv) << 16);
            *(uint4*)&M[(size_t)wid * 128 + cl] = o;
        }
    }
}

// ---------------------------------------------------------------------------
// fused GEMM: out = [M | X] @ Bt^T + bias  (K=256), optional ELU, bf16/f32 out.
// block = 64 rows x C cols; 4 waves as 2(row)x2(col); wave = 32 x C/2.
// (round-10 proven version)
// ---------------------------------------------------------------------------
template <int C, bool ELU, bool OUT_F32>
__global__ __launch_bounds__(256) void gemm_fused(
    const ushort_t* __restrict__ M, const ushort_t* __restrict__ X,
    const ushort_t* __restrict__ Bt, const float* __restrict__ bias,
    void* __restrict__ out_v, int nNodes) {
    constexpr int NI = C / 32;           // 16-col subtiles per wave
    const int tid = threadIdx.x;
    const int wave = tid >> 6, lane = tid & 63;
    const int lrow = lane & 15, lgrp = lane >> 4;
    const int rowbase = blockIdx.x * 64 + (wave >> 1) * 32;
    const int colbase = (wave & 1) * (C / 2);

    f32x4 acc[2][NI] = {};

#pragma unroll
    for (int half = 0; half < 2; ++half) {
        const ushort_t* A = half ? X : M;
#pragma unroll
        for (int ks = 0; ks < 4; ++ks) {
            const int k0 = ks * 32 + lgrp * 8;
            bf16x8 a[2], bf[NI];
#pragma unroll
            for (int mi = 0; mi < 2; ++mi) {
                int r = rowbase + mi * 16 + lrow;
                r = min(r, nNodes - 1);
                a[mi] = *(const bf16x8*)&A[(size_t)r * 128 + k0];
            }
#pragma unroll
            for (int ni = 0; ni < NI; ++ni) {
                int c = colbase + ni * 16 + lrow;
                bf[ni] = *(const bf16x8*)&Bt[(size_t)c * 256 + half * 128 + k0];
            }
#pragma unroll
            for (int mi = 0; mi < 2; ++mi)
#pragma unroll
                for (int ni = 0; ni < NI; ++ni)
                    acc[mi][ni] = __builtin_amdgcn_mfma_f32_16x16x32_bf16(
                        a[mi], bf[ni], acc[mi][ni], 0, 0, 0);
        }
    }

    // epilogue: C/D layout col=lane&15, row=(lane>>4)*4+reg (m89-verified)
#pragma unroll
    for (int ni = 0; ni < NI; ++ni) {
        const int c = colbase + ni * 16 + lrow;
        const float bv = bias[c];
#pragma unroll
        for (int mi = 0; mi < 2; ++mi) {
#pragma unroll
            for (int j = 0; j < 4; ++j) {
                int r = rowbase + mi * 16 + lgrp * 4 + j;
                if (r >= nNodes) continue;
                float v = acc[mi][ni][j] + bv;
                if (ELU) v = v > 0.f ? v : expm1f(v);
                if (OUT_F32) ((float*)out_v)[(size_t)r * C + c] = v;
                else ((ushort_t*)out_v)[(size_t)r * C + c] = f32_to_bf16(v);
            }
        }
    }
}

// ---------------------------------------------------------------------------
extern "C" void kernel_launch(void* const* d_in, const int* in_sizes, int n_in,
                              void* d_out, int out_size, void* d_ws, size_t ws_size,
                              hipStream_t stream) {
    const float* x = (const float*)d_in[0];
    const int* ei = (const int*)d_in[1];
    const int* src = ei;
    const int* dst = ei + N_EDGES;
    const float* Wl0 = (const float*)d_in[2];
    const float* Wr0 = (const float*)d_in[3];
    const float* b0 = (const float*)d_in[4];
    const float* Wl1 = (const float*)d_in[5];
    const float* Wr1 = (const float*)d_in[6];
    const float* b1 = (const float*)d_in[7];
    const float* Wl2 = (const float*)d_in[8];
    const float* Wr2 = (const float*)d_in[9];
    const float* b2 = (const float*)d_in[10];
    float* out = (float*)d_out;

    // workspace layout (int units)
    int* wsi = (int*)d_ws;
    int* offs = wsi;                               // 51200
    uint_t* gbcnt = (uint_t*)(offs + 51200);       // 256
    int* ebuf = (int*)(gbcnt + 256);               // 800000
    uint_t* gbuck = (uint_t*)(ebuf + 800000);      // NBUCK*BCAP = 1,003,520
    ushort_t* Bt0 = (ushort_t*)(gbuck + NBUCK * BCAP);  // 128*256
    ushort_t* Bt1 = Bt0 + 128 * 256;                    // 128*256
    ushort_t* Bt2 = Bt1 + 128 * 256;                    // 64*256
    const long long NB = (long long)N_NODES * 128;
    ushort_t* xb = Bt2 + 64 * 256;                 // [N*128] bf16
    ushort_t* Mb = xb + NB;                        // [N*128] bf16
    ushort_t* hA = Mb + NB;                        // [N*128] bf16
    ushort_t* hB = hA + NB;                        // [N*128] bf16

    // ---- prep: x->bf16 (+ gbcnt zero), stacked bf16 weights ----
    cvt_x<<<(N_NODES * 16 + 255) / 256, 256, 0, stream>>>(x, xb, gbcnt, N_NODES * 16);
    prep_all<<<(81920 + 255) / 256, 256, 0, stream>>>(
        Wl0, Wr0, Wl1, Wr1, Wl2, Wr2, Bt0, Bt1, Bt2);

    // ---- build CSR: 2 kernels ----
    binA<<<NBUCK, 256, 0, stream>>>(src, dst, gbcnt, gbuck);
    binB<<<NBUCK, 256, 0, stream>>>(gbcnt, gbuck, offs, ebuf);

    const int GATHER_GRID = 2048;                  // grid-stride, 4 waves/block
    const int GR = (N_NODES + 63) / 64;            // 782 node panels

    // ---- layer 0: M=agg(xb); hA = ELU([M|xb]@[Wl0;Wr0]+b0) ----
    gather_mean<<<GATHER_GRID, 256, 0, stream>>>(offs, ebuf, xb, Mb, N_NODES);
    gemm_fused<128, true, false><<<GR, 256, 0, stream>>>(
        Mb, xb, Bt0, b0, hA, N_NODES);

    // ---- layer 1: M=agg(hA); hB = ELU([M|hA]@[Wl1;Wr1]+b1) ----
    gather_mean<<<GATHER_GRID, 256, 0, stream>>>(offs, ebuf, hA, Mb, N_NODES);
    gemm_fused<128, true, false><<<GR, 256, 0, stream>>>(
        Mb, hA, Bt1, b1, hB, N_NODES);

    // ---- layer 2: M=agg(hB); out = [M|hB]@[Wl2;Wr2]+b2 (f32) ----
    gather_mean<<<GATHER_GRID, 256, 0, stream>>>(offs, ebuf, hB, Mb, N_NODES);
    gemm_fused<64, false, true><<<GR, 256, 0, stream>>>(
        Mb, hB, Bt2, b2, out, N_NODES);
}

// Round 14
// 203.872 us; speedup vs baseline: 1.1773x; 1.1232x over previous
//
#include <hip/hip_runtime.h>
#include <math.h>

#define N_NODES 50000
#define N_EDGES 800000
#define IN_CH 128
#define NBUCK 196        // ceil(50000/256): bucket = 256 consecutive dst nodes
#define BCAP 5120        // per-bucket capacity
#define EPB 4082         // edges per binA block: 196*4082 >= 800000

typedef unsigned short ushort_t;
typedef unsigned int uint_t;
typedef __attribute__((ext_vector_type(8))) short bf16x8;
typedef __attribute__((ext_vector_type(4))) float f32x4;

static __device__ __forceinline__ ushort_t f32_to_bf16(float f) {
    uint_t u = __float_as_uint(f);
    uint_t r = (u + 0x7fffu + ((u >> 16) & 1u)) >> 16;  // RNE
    return (ushort_t)r;
}

static __device__ __forceinline__ void acc8(float* a, uint4 v) {
    a[0] += __uint_as_float(v.x << 16); a[1] += __uint_as_float(v.x & 0xffff0000u);
    a[2] += __uint_as_float(v.y << 16); a[3] += __uint_as_float(v.y & 0xffff0000u);
    a[4] += __uint_as_float(v.z << 16); a[5] += __uint_as_float(v.z & 0xffff0000u);
    a[6] += __uint_as_float(v.w << 16); a[7] += __uint_as_float(v.w & 0xffff0000u);
}

static __device__ __forceinline__ void acc4(float* a, uint2 v) {
    a[0] += __uint_as_float(v.x << 16); a[1] += __uint_as_float(v.x & 0xffff0000u);
    a[2] += __uint_as_float(v.y << 16); a[3] += __uint_as_float(v.y & 0xffff0000u);
}

// ---------------------------------------------------------------------------
// Phase A: bin edges into 196 dst-range buckets. pair = (dst&255)<<16 | src
// ---------------------------------------------------------------------------
__global__ __launch_bounds__(256) void binA(
    const int* __restrict__ src, const int* __restrict__ dst,
    uint_t* __restrict__ gbcnt, uint_t* __restrict__ gbuck) {
    __shared__ uint_t hist[NBUCK];
    __shared__ uint_t excl_s[NBUCK];
    __shared__ uint_t gbase[NBUCK];
    __shared__ uint_t cur[NBUCK];
    __shared__ uint_t pfx[256];
    __shared__ uint_t stage[4096];
    __shared__ uint_t gpos[4096];
    const int t = threadIdx.x;
    const int e0 = blockIdx.x * EPB;
    const int e1 = min(e0 + EPB, N_EDGES);

    for (int i = t; i < NBUCK; i += 256) hist[i] = 0;
    __syncthreads();
    for (int e = e0 + t; e < e1; e += 256) atomicAdd(&hist[dst[e] >> 8], 1u);
    __syncthreads();
    uint_t own = (t < NBUCK) ? hist[t] : 0;
    pfx[t] = own;
    __syncthreads();
    for (int d = 1; d < 256; d <<= 1) {
        uint_t v = (t >= d) ? pfx[t - d] : 0;
        __syncthreads();
        pfx[t] += v;
        __syncthreads();
    }
    if (t < NBUCK) {
        uint_t excl = pfx[t] - own;
        excl_s[t] = excl;
        cur[t] = excl;
        gbase[t] = atomicAdd(&gbcnt[t], own);
    }
    __syncthreads();
    for (int e = e0 + t; e < e1; e += 256) {
        int d_ = dst[e];
        int b = d_ >> 8;
        uint_t p = atomicAdd(&cur[b], 1u);
        stage[p] = ((uint_t)(d_ & 255) << 16) | (uint_t)src[e];
        gpos[p] = (uint_t)b * BCAP + gbase[b] + (p - excl_s[b]);
    }
    __syncthreads();
    const int n = e1 - e0;
    for (int i = t; i < n; i += 256) gbuck[gpos[i]] = stage[i];
}

// ---------------------------------------------------------------------------
// Phase B (merged): per bucket -> offs (node CSR offsets) + ebuf (src lists).
// ---------------------------------------------------------------------------
__global__ __launch_bounds__(256) void binB(
    const uint_t* __restrict__ gbcnt, const uint_t* __restrict__ gbuck,
    int* __restrict__ offs, int* __restrict__ ebuf) {
    __shared__ uint_t pairs[BCAP];   // 20 KB
    __shared__ int stage[BCAP];      // 20 KB
    __shared__ uint_t bscan[256];
    __shared__ uint_t h[256];
    __shared__ uint_t psc[256];
    __shared__ int cur[256];
    const int b = blockIdx.x;
    const int t = threadIdx.x;

    uint_t g = (t < NBUCK) ? gbcnt[t] : 0;
    bscan[t] = g;
    __syncthreads();
    for (int d = 1; d < 256; d <<= 1) {
        uint_t v = (t >= d) ? bscan[t - d] : 0;
        __syncthreads();
        bscan[t] += v;
        __syncthreads();
    }
    const int base = (b > 0) ? (int)bscan[b - 1] : 0;
    const uint_t n = gbcnt[b];

    for (uint_t i = t; i < n; i += 256) pairs[i] = gbuck[(size_t)b * BCAP + i];
    h[t] = 0;
    __syncthreads();
    for (uint_t i = t; i < n; i += 256) atomicAdd(&h[(pairs[i] >> 16) & 255u], 1u);
    __syncthreads();
    uint_t own = h[t];
    psc[t] = own;
    __syncthreads();
    for (int d = 1; d < 256; d <<= 1) {
        uint_t v = (t >= d) ? psc[t - d] : 0;
        __syncthreads();
        psc[t] += v;
        __syncthreads();
    }
    const int excl = (int)(psc[t] - own);
    const int node = b * 256 + t;
    if (node <= N_NODES) offs[node] = base + excl;
    cur[t] = excl;
    __syncthreads();
    for (uint_t i = t; i < n; i += 256) {
        uint_t p = pairs[i];
        int l = (p >> 16) & 255;
        int pos = atomicAdd(&cur[l], 1);
        stage[pos] = (int)(p & 0xFFFFu);
    }
    __syncthreads();
    for (uint_t i = t; i < n; i += 256) ebuf[base + (int)i] = stage[i];
}

// ---------------------------------------------------------------------------
// convert x f32 -> bf16 (one pass); also zeroes gbcnt for binA
// ---------------------------------------------------------------------------
__global__ __launch_bounds__(256) void cvt_x(const float* __restrict__ x,
                                             ushort_t* __restrict__ xb,
                                             uint_t* __restrict__ gbcnt, int n8) {
    int i = blockIdx.x * 256 + threadIdx.x;
    if (blockIdx.x == 0 && threadIdx.x < NBUCK) gbcnt[threadIdx.x] = 0;
    if (i >= n8) return;
    const float* p = x + (size_t)i * 8;
    float4 lo = *(const float4*)p;
    float4 hi = *(const float4*)(p + 4);
    bf16x8 r;
    r[0] = (short)f32_to_bf16(lo.x); r[1] = (short)f32_to_bf16(lo.y);
    r[2] = (short)f32_to_bf16(lo.z); r[3] = (short)f32_to_bf16(lo.w);
    r[4] = (short)f32_to_bf16(hi.x); r[5] = (short)f32_to_bf16(hi.y);
    r[6] = (short)f32_to_bf16(hi.z); r[7] = (short)f32_to_bf16(hi.w);
    *(bf16x8*)&xb[(size_t)i * 8] = r;
}

// ---------------------------------------------------------------------------
// weight prep: Bt0/Bt1 = [Wl;Wr] stacked K=256, K-contiguous, bf16.
// Bt2s = layer-2 col-split: c<64 -> Wl2[k][c], c>=64 -> Wr2[k][c-64], K=128.
// ---------------------------------------------------------------------------
__global__ __launch_bounds__(256) void prep_all(
    const float* __restrict__ Wl0, const float* __restrict__ Wr0,
    const float* __restrict__ Wl1, const float* __restrict__ Wr1,
    const float* __restrict__ Wl2, const float* __restrict__ Wr2,
    ushort_t* __restrict__ Bt0, ushort_t* __restrict__ Bt1,
    ushort_t* __restrict__ Bt2s) {
    int i = blockIdx.x * 256 + threadIdx.x;
    if (i < 32768) {
        int c = i / 256, k = i % 256;
        float v = (k < 128) ? Wl0[(size_t)k * 128 + c] : Wr0[(size_t)(k - 128) * 128 + c];
        Bt0[i] = f32_to_bf16(v);
    } else if (i < 65536) {
        i -= 32768;
        int c = i / 256, k = i % 256;
        float v = (k < 128) ? Wl1[(size_t)k * 128 + c] : Wr1[(size_t)(k - 128) * 128 + c];
        Bt1[i] = f32_to_bf16(v);
    } else if (i < 81920) {
        i -= 65536;
        int c = i >> 7, k = i & 127;   // 128 cols x 128 k
        float v = (c < 64) ? Wl2[(size_t)k * 64 + c] : Wr2[(size_t)k * 64 + (c - 64)];
        Bt2s[i] = f32_to_bf16(v);
    }
}

// ---------------------------------------------------------------------------
// mean-aggregate gather: M[node] = mean(feat[neighbors]) (bf16 in/out).
// ROUND-9 PROVEN VERSION: quarter q owns neighbor j+4k+q; 16B/lane;
// 8 neighbors (2KB) in flight per round. Grid-stride, 4 waves/block.
// ---------------------------------------------------------------------------
__global__ __launch_bounds__(256) void gather_mean(
    const int* __restrict__ offs, const int* __restrict__ ebuf,
    const ushort_t* __restrict__ feat, ushort_t* __restrict__ M, int nNodes) {
    const int wl = threadIdx.x >> 6;
    const int lane = threadIdx.x & 63;
    const int q = lane >> 4;           // quarter owns neighbor j+q (stride 4)
    const int cl = (lane & 15) * 8;    // 8 channels per lane
    const int nw = gridDim.x * 4;

    for (int wid = blockIdx.x * 4 + wl; wid < nNodes; wid += nw) {
        const int o0 = offs[wid], o1 = offs[wid + 1];
        const float inv = 1.0f / fmaxf((float)(o1 - o0), 1.0f);
        float a0[8] = {0.f, 0.f, 0.f, 0.f, 0.f, 0.f, 0.f, 0.f};
        float a1[8] = {0.f, 0.f, 0.f, 0.f, 0.f, 0.f, 0.f, 0.f};
        int j = o0;
        for (; j + 8 <= o1; j += 8) {
            int s0 = ebuf[j + q];
            int s1 = ebuf[j + 4 + q];
            uint4 v0 = *(const uint4*)&feat[(size_t)s0 * 128 + cl];
            uint4 v1 = *(const uint4*)&feat[(size_t)s1 * 128 + cl];
            acc8(a0, v0);
            acc8(a1, v1);
        }
        if (j + 4 <= o1) {
            int s0 = ebuf[j + q];
            uint4 v0 = *(const uint4*)&feat[(size_t)s0 * 128 + cl];
            acc8(a0, v0);
            j += 4;
        }
        if (j + q < o1) {
            int s1 = ebuf[j + q];
            uint4 v1 = *(const uint4*)&feat[(size_t)s1 * 128 + cl];
            acc8(a1, v1);
        }
#pragma unroll
        for (int k = 0; k < 8; ++k) a0[k] += a1[k];
#pragma unroll
        for (int k = 0; k < 8; ++k) {
            a0[k] += __shfl_xor(a0[k], 16);
            a0[k] += __shfl_xor(a0[k], 32);
        }
        if (lane < 16) {
            uint4 o;
            o.x = (uint_t)f32_to_bf16(a0[0] * inv) | ((uint_t)f32_to_bf16(a0[1] * inv) << 16);
            o.y = (uint_t)f32_to_bf16(a0[2] * inv) | ((uint_t)f32_to_bf16(a0[3] * inv) << 16);
            o.z = (uint_t)f32_to_bf16(a0[4] * inv) | ((uint_t)f32_to_bf16(a0[5] * inv) << 16);
            o.w = (uint_t)f32_to_bf16(a0[6] * inv) | ((uint_t)f32_to_bf16(a0[7] * inv) << 16);
            *(uint4*)&M[(size_t)wid * 128 + cl] = o;
        }
    }
}

// ---------------------------------------------------------------------------
// fused GEMM (ROUND-9 PROVEN dual-y): out = [M|X] @ Bt^T + bias (K=256), ELU,
// bf16 out. block = 64 rows x 64 cols, 4 waves as 2x2 of 32x32 tiles.
// ---------------------------------------------------------------------------
__global__ __launch_bounds__(256) void gemm_fused128(
    const ushort_t* __restrict__ M, const ushort_t* __restrict__ X,
    const ushort_t* __restrict__ Bt, const float* __restrict__ bias,
    ushort_t* __restrict__ out_b, int nNodes) {
    const int tid = threadIdx.x;
    const int wave = tid >> 6, lane = tid & 63;
    const int lrow = lane & 15, lgrp = lane >> 4;
    const int rowbase = blockIdx.x * 64 + (wave >> 1) * 32;
    const int colbase = blockIdx.y * 64 + (wave & 1) * 32;

    f32x4 acc[2][2] = {};

#pragma unroll
    for (int half = 0; half < 2; ++half) {
        const ushort_t* A = half ? X : M;
#pragma unroll
        for (int ks = 0; ks < 4; ++ks) {
            const int k0 = ks * 32 + lgrp * 8;
            bf16x8 a[2], bf[2];
#pragma unroll
            for (int mi = 0; mi < 2; ++mi) {
                int r = rowbase + mi * 16 + lrow;
                r = min(r, nNodes - 1);
                a[mi] = *(const bf16x8*)&A[(size_t)r * 128 + k0];
            }
#pragma unroll
            for (int ni = 0; ni < 2; ++ni) {
                int c = colbase + ni * 16 + lrow;
                bf[ni] = *(const bf16x8*)&Bt[(size_t)c * 256 + half * 128 + k0];
            }
#pragma unroll
            for (int mi = 0; mi < 2; ++mi)
#pragma unroll
                for (int ni = 0; ni < 2; ++ni)
                    acc[mi][ni] = __builtin_amdgcn_mfma_f32_16x16x32_bf16(
                        a[mi], bf[ni], acc[mi][ni], 0, 0, 0);
        }
    }

    // epilogue: C/D layout col=lane&15, row=(lane>>4)*4+reg (m89-verified)
#pragma unroll
    for (int ni = 0; ni < 2; ++ni) {
        const int c = colbase + ni * 16 + lrow;
        const float bv = bias[c];
#pragma unroll
        for (int mi = 0; mi < 2; ++mi) {
#pragma unroll
            for (int j = 0; j < 4; ++j) {
                int r = rowbase + mi * 16 + lgrp * 4 + j;
                if (r >= nNodes) continue;
                float v = acc[mi][ni][j] + bv;
                v = v > 0.f ? v : expm1f(v);
                out_b[(size_t)r * 128 + c] = f32_to_bf16(v);
            }
        }
    }
}

// ---------------------------------------------------------------------------
// layer-2 split GEMM: K=128, C=128 stacked cols.
// wave&1==0 -> cols 0..63  = hB@Wl2        -> pl (bf16)
// wave&1==1 -> cols 64..127 = hB@Wr2 + b2  -> pr (f32)
// ---------------------------------------------------------------------------
__global__ __launch_bounds__(256) void gemm_split(
    const ushort_t* __restrict__ X, const ushort_t* __restrict__ Bt2s,
    const float* __restrict__ bias, ushort_t* __restrict__ pl,
    float* __restrict__ pr, int nNodes) {
    const int tid = threadIdx.x;
    const int wave = tid >> 6, lane = tid & 63;
    const int lrow = lane & 15, lgrp = lane >> 4;
    const int rowbase = blockIdx.x * 64 + (wave >> 1) * 32;
    const int colbase = (wave & 1) * 64;

    f32x4 acc[2][4] = {};

#pragma unroll
    for (int ks = 0; ks < 4; ++ks) {
        const int k0 = ks * 32 + lgrp * 8;
        bf16x8 a[2], bf[4];
#pragma unroll
        for (int mi = 0; mi < 2; ++mi) {
            int r = rowbase + mi * 16 + lrow;
            r = min(r, nNodes - 1);
            a[mi] = *(const bf16x8*)&X[(size_t)r * 128 + k0];
        }
#pragma unroll
        for (int ni = 0; ni < 4; ++ni) {
            int c = colbase + ni * 16 + lrow;
            bf[ni] = *(const bf16x8*)&Bt2s[(size_t)c * 128 + k0];
        }
#pragma unroll
        for (int mi = 0; mi < 2; ++mi)
#pragma unroll
            for (int ni = 0; ni < 4; ++ni)
                acc[mi][ni] = __builtin_amdgcn_mfma_f32_16x16x32_bf16(
                    a[mi], bf[ni], acc[mi][ni], 0, 0, 0);
    }

    const bool is_pr = (wave & 1) != 0;  // wave-uniform
#pragma unroll
    for (int ni = 0; ni < 4; ++ni) {
        const int c = colbase + ni * 16 + lrow;
        const float bv = is_pr ? bias[c - 64] : 0.f;
#pragma unroll
        for (int mi = 0; mi < 2; ++mi) {
#pragma unroll
            for (int j = 0; j < 4; ++j) {
                int r = rowbase + mi * 16 + lgrp * 4 + j;
                if (r >= nNodes) continue;
                float v = acc[mi][ni][j];
                if (is_pr) pr[(size_t)r * 64 + (c - 64)] = v + bv;
                else pl[(size_t)r * 64 + c] = f32_to_bf16(v);
            }
        }
    }
}

// ---------------------------------------------------------------------------
// final gather: out[n] = mean(pl[neighbors]) + pr[n]  (pl bf16 64ch, out f32)
// round-9 loop structure, uint2 (4ch) per lane.
// ---------------------------------------------------------------------------
__global__ __launch_bounds__(256) void gather64_final(
    const int* __restrict__ offs, const int* __restrict__ ebuf,
    const ushort_t* __restrict__ pl, const float* __restrict__ pr,
    float* __restrict__ out, int nNodes) {
    const int wl = threadIdx.x >> 6;
    const int lane = threadIdx.x & 63;
    const int q = lane >> 4;           // quarter owns neighbor j+q (stride 4)
    const int cl = (lane & 15) * 4;    // 4 channels per lane
    const int nw = gridDim.x * 4;

    for (int wid = blockIdx.x * 4 + wl; wid < nNodes; wid += nw) {
        const int o0 = offs[wid], o1 = offs[wid + 1];
        const float inv = 1.0f / fmaxf((float)(o1 - o0), 1.0f);
        float a0[4] = {0.f, 0.f, 0.f, 0.f};
        float a1[4] = {0.f, 0.f, 0.f, 0.f};
        int j = o0;
        for (; j + 8 <= o1; j += 8) {
            int s0 = ebuf[j + q];
            int s1 = ebuf[j + 4 + q];
            uint2 v0 = *(const uint2*)&pl[(size_t)s0 * 64 + cl];
            uint2 v1 = *(const uint2*)&pl[(size_t)s1 * 64 + cl];
            acc4(a0, v0);
            acc4(a1, v1);
        }
        if (j + 4 <= o1) {
            int s0 = ebuf[j + q];
            uint2 v0 = *(const uint2*)&pl[(size_t)s0 * 64 + cl];
            acc4(a0, v0);
            j += 4;
        }
        if (j + q < o1) {
            int s1 = ebuf[j + q];
            uint2 v1 = *(const uint2*)&pl[(size_t)s1 * 64 + cl];
            acc4(a1, v1);
        }
#pragma unroll
        for (int k = 0; k < 4; ++k) a0[k] += a1[k];
#pragma unroll
        for (int k = 0; k < 4; ++k) {
            a0[k] += __shfl_xor(a0[k], 16);
            a0[k] += __shfl_xor(a0[k], 32);
        }
        if (lane < 16) {
            float4 pv = *(const float4*)&pr[(size_t)wid * 64 + cl];
            float4 o;
            o.x = a0[0] * inv + pv.x;
            o.y = a0[1] * inv + pv.y;
            o.z = a0[2] * inv + pv.z;
            o.w = a0[3] * inv + pv.w;
            *(float4*)&out[(size_t)wid * 64 + cl] = o;
        }
    }
}

// ---------------------------------------------------------------------------
extern "C" void kernel_launch(void* const* d_in, const int* in_sizes, int n_in,
                              void* d_out, int out_size, void* d_ws, size_t ws_size,
                              hipStream_t stream) {
    const float* x = (const float*)d_in[0];
    const int* ei = (const int*)d_in[1];
    const int* src = ei;
    const int* dst = ei + N_EDGES;
    const float* Wl0 = (const float*)d_in[2];
    const float* Wr0 = (const float*)d_in[3];
    const float* b0 = (const float*)d_in[4];
    const float* Wl1 = (const float*)d_in[5];
    const float* Wr1 = (const float*)d_in[6];
    const float* b1 = (const float*)d_in[7];
    const float* Wl2 = (const float*)d_in[8];
    const float* Wr2 = (const float*)d_in[9];
    const float* b2 = (const float*)d_in[10];
    float* out = (float*)d_out;

    // workspace layout (int units)
    int* wsi = (int*)d_ws;
    int* offs = wsi;                               // 51200
    uint_t* gbcnt = (uint_t*)(offs + 51200);       // 256
    int* ebuf = (int*)(gbcnt + 256);               // 800000
    uint_t* gbuck = (uint_t*)(ebuf + 800000);      // NBUCK*BCAP = 1,003,520
    ushort_t* Bt0 = (ushort_t*)(gbuck + NBUCK * BCAP);  // 128*256
    ushort_t* Bt1 = Bt0 + 128 * 256;                    // 128*256
    ushort_t* Bt2s = Bt1 + 128 * 256;                   // 128*128
    const long long NB = (long long)N_NODES * 128;
    ushort_t* xb = Bt2s + 128 * 128;               // [N*128] bf16
    ushort_t* Mb = xb + NB;                        // [N*128] bf16
    ushort_t* hA = Mb + NB;                        // [N*128] bf16
    ushort_t* hB = hA + NB;                        // [N*128] bf16
    ushort_t* pl = hB + NB;                        // [N*64] bf16
    float* pr = (float*)(pl + (long long)N_NODES * 64);  // [N*64] f32

    // ---- prep: x->bf16 (+ gbcnt zero), stacked bf16 weights ----
    cvt_x<<<(N_NODES * 16 + 255) / 256, 256, 0, stream>>>(x, xb, gbcnt, N_NODES * 16);
    prep_all<<<(81920 + 255) / 256, 256, 0, stream>>>(
        Wl0, Wr0, Wl1, Wr1, Wl2, Wr2, Bt0, Bt1, Bt2s);

    // ---- build CSR: 2 kernels ----
    binA<<<NBUCK, 256, 0, stream>>>(src, dst, gbcnt, gbuck);
    binB<<<NBUCK, 256, 0, stream>>>(gbcnt, gbuck, offs, ebuf);

    const int GATHER_GRID = 2048;                  // grid-stride, 4 waves/block
    const int GR = (N_NODES + 63) / 64;            // 782 node panels

    // ---- layer 0: M=agg(xb); hA = ELU([M|xb]@[Wl0;Wr0]+b0) ----
    gather_mean<<<GATHER_GRID, 256, 0, stream>>>(offs, ebuf, xb, Mb, N_NODES);
    gemm_fused128<<<dim3(GR, 2), 256, 0, stream>>>(Mb, xb, Bt0, b0, hA, N_NODES);

    // ---- layer 1: M=agg(hA); hB = ELU([M|hA]@[Wl1;Wr1]+b1) ----
    gather_mean<<<GATHER_GRID, 256, 0, stream>>>(offs, ebuf, hA, Mb, N_NODES);
    gemm_fused128<<<dim3(GR, 2), 256, 0, stream>>>(Mb, hA, Bt1, b1, hB, N_NODES);

    // ---- layer 2 (project-then-aggregate): pl=hB@Wl2, pr=hB@Wr2+b2;
    //      out = mean-gather(pl) + pr ----
    gemm_split<<<GR, 256, 0, stream>>>(hB, Bt2s, b2, pl, pr, N_NODES);
    gather64_final<<<GATHER_GRID, 256, 0, stream>>>(offs, ebuf, pl, pr, out, N_NODES);
}